// Round 9
// baseline (347.527 us; speedup 1.0000x reference)
//
#include <hip/hip_runtime.h>
#include <hip/hip_bf16.h>

#define S_LEN 2048
#define NHEAD 16
#define HDIM 64
#define EMB 1024

typedef short v8s __attribute__((ext_vector_type(8)));
typedef float v4f __attribute__((ext_vector_type(4)));

__device__ __forceinline__ float bflo(unsigned u) {
    union { unsigned u; float f; } v; v.u = u << 16; return v.f;
}
__device__ __forceinline__ float bfhi(unsigned u) {
    union { unsigned u; float f; } v; v.u = u & 0xFFFF0000u; return v.f;
}
// packed f32x2 -> bf16x2 (v_cvt_pk_bf16_f32 on gfx950), RNE
__device__ __forceinline__ unsigned cvtpk(float lo, float hi) {
    union { __hip_bfloat162 h2; unsigned u; } v;
    float2 f; f.x = lo; f.y = hi;
    v.h2 = __float22bfloat162_rn(f);
    return v.u;
}
__device__ __forceinline__ unsigned short f2bf(float f) {
    return (unsigned short)cvtpk(f, f);
}
__device__ __forceinline__ v8s cvt8(float4 a, float4 b) {
    v8s r;
    ((unsigned*)&r)[0] = cvtpk(a.x, a.y);
    ((unsigned*)&r)[1] = cvtpk(a.z, a.w);
    ((unsigned*)&r)[2] = cvtpk(b.x, b.y);
    ((unsigned*)&r)[3] = cvtpk(b.z, b.w);
    return r;
}

// ---------------------------------------------------------------------------
// K1: MFMA projections (unchanged from R8).
// ---------------------------------------------------------------------------
__global__ __launch_bounds__(128) void k_proj2(
    const float* __restrict__ q, const float* __restrict__ k, const float* __restrict__ v,
    const float* __restrict__ Wq, const float* __restrict__ Wk, const float* __restrict__ Wv,
    unsigned short* __restrict__ Qp, unsigned short* __restrict__ Kp, unsigned short* __restrict__ Vt)
{
    __shared__ unsigned short Tq[2][16][72];
    const int t = threadIdx.x, wave = t >> 6, lane = t & 63;
    const int l15 = lane & 15, l4 = lane >> 4;
    const int mtx = blockIdx.y;
    const int hq = blockIdx.z;
    const int row0 = blockIdx.x * 32 + wave * 16;
    const int b = row0 >> 11, s0 = row0 & 2047;
    const float* X = (mtx == 0) ? q : (mtx == 1) ? k : v;
    const float* W = (mtx == 0) ? Wq : (mtx == 1) ? Wk : Wv;

    v8s wf[4][2];
    #pragma unroll
    for (int tile = 0; tile < 4; ++tile)
        #pragma unroll
        for (int c2 = 0; c2 < 2; ++c2) {
            const float* wp = W + (tile * 16 + l15) * 64 + c2 * 32 + l4 * 8;
            wf[tile][c2] = cvt8(*(const float4*)wp, *(const float4*)(wp + 4));
        }

    #pragma unroll
    for (int hi = 0; hi < 4; ++hi) {
        const int h = hq * 4 + hi;
        v8s xf[2];
        #pragma unroll
        for (int c2 = 0; c2 < 2; ++c2) {
            const float* xp = X + (size_t)(row0 + l15) * EMB + h * 64 + c2 * 32 + l4 * 8;
            xf[c2] = cvt8(*(const float4*)xp, *(const float4*)(xp + 4));
        }
        v4f acc[4];
        #pragma unroll
        for (int i = 0; i < 4; ++i) acc[i] = (v4f){0.f, 0.f, 0.f, 0.f};
        if (mtx < 2) {
            #pragma unroll
            for (int ns = 0; ns < 4; ++ns)
                #pragma unroll
                for (int c2 = 0; c2 < 2; ++c2)
                    acc[ns] = __builtin_amdgcn_mfma_f32_16x16x32_bf16(xf[c2], wf[ns][c2], acc[ns], 0, 0, 0);
            #pragma unroll
            for (int ns = 0; ns < 4; ++ns)
                #pragma unroll
                for (int r = 0; r < 4; ++r)
                    Tq[wave][l4 * 4 + r][ns * 16 + l15] = f2bf(acc[ns][r]);
            const int row = lane >> 2, c8 = (lane & 3) * 16;
            uint4 d0 = *(const uint4*)&Tq[wave][row][c8];
            uint4 d1 = *(const uint4*)&Tq[wave][row][c8 + 8];
            unsigned short* dst = ((mtx == 0) ? Qp : Kp)
                + (size_t)(b * NHEAD + h) * S_LEN * HDIM + (size_t)(s0 + row) * HDIM + c8;
            *(uint4*)dst = d0;
            *(uint4*)(dst + 8) = d1;
        } else {
            #pragma unroll
            for (int ms = 0; ms < 4; ++ms)
                #pragma unroll
                for (int c2 = 0; c2 < 2; ++c2)
                    acc[ms] = __builtin_amdgcn_mfma_f32_16x16x32_bf16(wf[ms][c2], xf[c2], acc[ms], 0, 0, 0);
            unsigned short* dst = Vt + (size_t)(b * NHEAD + h) * HDIM * S_LEN;
            #pragma unroll
            for (int ms = 0; ms < 4; ++ms)
                #pragma unroll
                for (int r = 0; r < 4; ++r)
                    dst[(size_t)(ms * 16 + l4 * 4 + r) * S_LEN + s0 + l15] = f2bf(acc[ms][r]);
        }
    }
}

// ---------------------------------------------------------------------------
// K1c: W_fc fp32 -> bf16
// ---------------------------------------------------------------------------
__global__ __launch_bounds__(256) void k_cvtw(
    const float* __restrict__ W, unsigned short* __restrict__ Wb)
{
    const int i = (blockIdx.x * 256 + threadIdx.x) * 4;
    float4 wv = *(const float4*)(W + i);
    uint2 pk;
    pk.x = cvtpk(wv.x, wv.y);
    pk.y = cvtpk(wv.z, wv.w);
    *(uint2*)(Wb + i) = pk;
}

// ---------------------------------------------------------------------------
// K2: fused attention v3. Key change vs R8: compute S^T = K·Q^T so the MFMA
// C-fragment holds 4 CONSECUTIVE k at one q per lane -> exp'd scores stage to
// LDS as single ds_write_b64 in A/B-frag element order (R8 used 4 scalar
// ds_write_b16 per frag = LDS-issue-bound, 4.3M conflict cycles). PV computes
// O^T = V^T·P^T (A=Vt rows, same global loads). k-chunk 64 -> 8 c-iters,
// 17 barriers (was 32). Column perm ((l15+rg*4+ks*8)&15) makes phase-3 reads
// 2-way (free). Epilogue bounces O^T through stride-18 LDS plane -> 128B
// coalesced stores. LDS 144 KiB, 1 block/CU, VGPR ~64 + 64 acc.
// ---------------------------------------------------------------------------
__global__ __launch_bounds__(1024, 4) void k_fattn(
    const unsigned short* __restrict__ Qp, const unsigned short* __restrict__ Kp,
    const unsigned short* __restrict__ Vt, unsigned short* __restrict__ Op)
{
    __shared__ uint2 LDSU[18432];          // 144 KiB
    uint2* PexF = LDSU;                    // [16 heads][1024]: (qs*4+ks)*64 + permuted lane
    uint2* ZrF  = LDSU + 16384;            // [1024], elementwise mirror of PexF reduce
    const int t = threadIdx.x, wave = t >> 6, lane = t & 63;
    const int l15 = lane & 15, l4 = lane >> 4;
    const int h = wave;
    const int id = blockIdx.x;
    const int slot = id & 7;
    const int kqb = slot & 3;
    const int bsel = slot >> 2;
    const int qt = bsel * 32 + (id >> 3);
    const int b = qt >> 5;
    const int q0 = (qt & 31) * 64;
    const unsigned short* qh = Qp + (size_t)(b * NHEAD + h) * S_LEN * HDIM;
    const unsigned short* kh = Kp + (size_t)(b * NHEAD + h) * S_LEN * HDIM;
    const unsigned short* vh = Vt + (size_t)(b * NHEAD + h) * HDIM * S_LEN;

    v8s aq[4][2];
    #pragma unroll
    for (int qs = 0; qs < 4; ++qs)
        #pragma unroll
        for (int c2 = 0; c2 < 2; ++c2)
            aq[qs][c2] = *(const v8s*)(qh + (size_t)(q0 + qs * 16 + l15) * HDIM + c2 * 32 + l4 * 8);

    v4f o[4][4];
    #pragma unroll
    for (int qs = 0; qs < 4; ++qs)
        #pragma unroll
        for (int ds = 0; ds < 4; ++ds)
            o[qs][ds] = (v4f){0.f, 0.f, 0.f, 0.f};

    uint2* myP = PexF + h * 1024;
    const float SC = 0.03125f;

    for (int c = 0; c < 8; ++c) {
        const int kk0 = kqb * 512 + c * 64;
        // ---- phase 1: S^T = K·Q^T, exp -> packed b64 frag-layout stores ----
        #pragma unroll
        for (int ks = 0; ks < 4; ++ks) {
            const unsigned short* kb = kh + (size_t)(kk0 + ks * 16 + l15) * HDIM + l4 * 8;
            v8s ka0 = *(const v8s*)kb;
            v8s ka1 = *(const v8s*)(kb + 32);
            const int wcol = l4 * 16 + ((l15 + l4 * 4 + ks * 8) & 15);
            #pragma unroll
            for (int qs = 0; qs < 4; ++qs) {
                v4f sf = (v4f){0.f, 0.f, 0.f, 0.f};
                sf = __builtin_amdgcn_mfma_f32_16x16x32_bf16(ka0, aq[qs][0], sf, 0, 0, 0);
                sf = __builtin_amdgcn_mfma_f32_16x16x32_bf16(ka1, aq[qs][1], sf, 0, 0, 0);
                uint2 pe;
                pe.x = cvtpk(__expf(sf[0] * SC), __expf(sf[1] * SC));
                pe.y = cvtpk(__expf(sf[2] * SC), __expf(sf[3] * SC));
                myP[(qs * 4 + ks) * 64 + wcol] = pe;     // 4 consecutive k @ one q
            }
        }
        __syncthreads();
        // ---- phase 2: Zr = 1/sum_h exp, elementwise over flat index t ----
        {
            uint2 u = PexF[t];
            float z0 = bflo(u.x), z1 = bfhi(u.x), z2 = bflo(u.y), z3 = bfhi(u.y);
            #pragma unroll
            for (int hh = 1; hh < 16; ++hh) {
                u = PexF[hh * 1024 + t];
                z0 += bflo(u.x); z1 += bfhi(u.x); z2 += bflo(u.y); z3 += bfhi(u.y);
            }
            uint2 zo;
            zo.x = cvtpk(__builtin_amdgcn_rcpf(z0), __builtin_amdgcn_rcpf(z1));
            zo.y = cvtpk(__builtin_amdgcn_rcpf(z2), __builtin_amdgcn_rcpf(z3));
            ZrF[t] = zo;
        }
        __syncthreads();
        // ---- phase 3: pn = P .* Zr (already frag-ordered), O^T += V^T·P^T ----
        #pragma unroll
        for (int kp = 0; kp < 2; ++kp) {
            v8s bv[4];
            #pragma unroll
            for (int ds = 0; ds < 4; ++ds)
                bv[ds] = *(const v8s*)(vh + (size_t)(ds * 16 + l15) * S_LEN + kk0 + kp * 32 + l4 * 8);
            const int ks_s = kp * 2 + (l4 >> 1);
            const int rg0 = (l4 & 1) * 2;
            const int i0 = ks_s * 64 + rg0 * 16 + ((l15 + rg0 * 4 + ks_s * 8) & 15);
            const int i1 = ks_s * 64 + (rg0 + 1) * 16 + ((l15 + (rg0 + 1) * 4 + ks_s * 8) & 15);
            #pragma unroll
            for (int qs = 0; qs < 4; ++qs) {
                const int base = qs * 256;
                uint2 pa = myP[base + i0], pb = myP[base + i1];
                uint2 za = ZrF[base + i0], zb = ZrF[base + i1];
                v8s pn;
                ((unsigned*)&pn)[0] = cvtpk(bflo(pa.x) * bflo(za.x), bfhi(pa.x) * bfhi(za.x));
                ((unsigned*)&pn)[1] = cvtpk(bflo(pa.y) * bflo(za.y), bfhi(pa.y) * bfhi(za.y));
                ((unsigned*)&pn)[2] = cvtpk(bflo(pb.x) * bflo(zb.x), bfhi(pb.x) * bfhi(zb.x));
                ((unsigned*)&pn)[3] = cvtpk(bflo(pb.y) * bflo(zb.y), bfhi(pb.y) * bfhi(zb.y));
                #pragma unroll
                for (int ds = 0; ds < 4; ++ds)
                    o[qs][ds] = __builtin_amdgcn_mfma_f32_16x16x32_bf16(bv[ds], pn, o[qs][ds], 0, 0, 0);
            }
        }
        // no 3rd barrier: myP is wave-private; ZrF rewrite ordered by next
        // iteration's two barriers.
    }

    // ---- epilogue: O^T C-frags -> per-wave LDS plane (stride 18) -> 128B
    // coalesced stores. Barrier required: epilogue planes (1152/wave) overlap
    // neighbor PexF planes + ZrF.
    __syncthreads();
    uint2* myE = LDSU + h * 1152;
    #pragma unroll
    for (int qs = 0; qs < 4; ++qs)
        #pragma unroll
        for (int ds = 0; ds < 4; ++ds) {
            uint2 wv;
            wv.x = cvtpk(o[qs][ds][0], o[qs][ds][1]);
            wv.y = cvtpk(o[qs][ds][2], o[qs][ds][3]);
            myE[(qs * 16 + l15) * 18 + ds * 4 + l4] = wv;
        }
    unsigned short* op = Op + (size_t)(kqb * 2 + b) * S_LEN * EMB + (size_t)q0 * EMB + h * 64;
    #pragma unroll
    for (int it = 0; it < 8; ++it) {
        const int qr = it * 8 + (lane >> 3);
        uint4 dv = *(const uint4*)&myE[qr * 18 + (lane & 7) * 2];
        *(uint4*)(op + (size_t)qr * EMB + (lane & 7) * 8) = dv;
    }
}

// ---------------------------------------------------------------------------
// K2b: merge the 4 k-quarter partials -> AO[b*2048+s][e] bf16
// ---------------------------------------------------------------------------
__global__ __launch_bounds__(256) void k_merge4(
    const unsigned short* __restrict__ Op, unsigned short* __restrict__ AO)
{
    const size_t i = ((size_t)blockIdx.x * 256 + threadIdx.x) * 8;
    const size_t row = i >> 10;
    const int b = (int)(row >> 11);
    const size_t off = (row & 2047) * EMB + (i & 1023);
    float a0 = 0, a1 = 0, a2 = 0, a3 = 0, a4 = 0, a5 = 0, a6 = 0, a7 = 0;
    #pragma unroll
    for (int kq = 0; kq < 4; ++kq) {
        uint4 u = *(const uint4*)(Op + (size_t)(kq * 2 + b) * S_LEN * EMB + off);
        a0 += bflo(u.x); a1 += bfhi(u.x);
        a2 += bflo(u.y); a3 += bfhi(u.y);
        a4 += bflo(u.z); a5 += bfhi(u.z);
        a6 += bflo(u.w); a7 += bfhi(u.w);
    }
    uint4 r;
    r.x = cvtpk(a0, a1); r.y = cvtpk(a2, a3);
    r.z = cvtpk(a4, a5); r.w = cvtpk(a6, a7);
    *(uint4*)(AO + i) = r;
}

// ---------------------------------------------------------------------------
// K4: out = AO @ W_fc^T + b_fc  (unchanged from R8)
// ---------------------------------------------------------------------------
__global__ __launch_bounds__(256) void k_fc(
    const unsigned short* __restrict__ AO, const unsigned short* __restrict__ Wb,
    const float* __restrict__ bias, float* __restrict__ out)
{
    const int t = threadIdx.x, wave = t >> 6, lane = t & 63;
    const int l15 = lane & 15, l4 = lane >> 4;
    const int m0 = blockIdx.x * 128 + wave * 32;
    const int n0 = blockIdx.y * 64;
    v4f c[2][4];
    #pragma unroll
    for (int i = 0; i < 2; ++i)
        #pragma unroll
        for (int j = 0; j < 4; ++j) c[i][j] = (v4f){0.f, 0.f, 0.f, 0.f};
    for (int k = 0; k < EMB; k += 32) {
        v8s a0 = *(const v8s*)(AO + (size_t)(m0 + l15) * EMB + k + l4 * 8);
        v8s a1 = *(const v8s*)(AO + (size_t)(m0 + 16 + l15) * EMB + k + l4 * 8);
        #pragma unroll
        for (int ns = 0; ns < 4; ++ns) {
            v8s bw = *(const v8s*)(Wb + (size_t)(n0 + ns * 16 + l15) * EMB + k + l4 * 8);
            c[0][ns] = __builtin_amdgcn_mfma_f32_16x16x32_bf16(a0, bw, c[0][ns], 0, 0, 0);
            c[1][ns] = __builtin_amdgcn_mfma_f32_16x16x32_bf16(a1, bw, c[1][ns], 0, 0, 0);
        }
    }
    #pragma unroll
    for (int ms = 0; ms < 2; ++ms)
        #pragma unroll
        for (int ns = 0; ns < 4; ++ns) {
            const float bv = bias[n0 + ns * 16 + l15];
            #pragma unroll
            for (int r = 0; r < 4; ++r)
                out[(size_t)(m0 + ms * 16 + l4 * 4 + r) * EMB + n0 + ns * 16 + l15] = c[ms][ns][r] + bv;
        }
}

extern "C" void kernel_launch(void* const* d_in, const int* in_sizes, int n_in,
                              void* d_out, int out_size, void* d_ws, size_t ws_size,
                              hipStream_t stream)
{
    (void)in_sizes; (void)n_in; (void)out_size; (void)ws_size;
    const float* q   = (const float*)d_in[0];
    const float* k   = (const float*)d_in[1];
    const float* v   = (const float*)d_in[2];
    const float* Wq  = (const float*)d_in[3];
    const float* Wk  = (const float*)d_in[4];
    const float* Wv  = (const float*)d_in[5];
    const float* Wfc = (const float*)d_in[6];
    const float* bfc = (const float*)d_in[7];

    char* w = (char*)d_ws;
    unsigned short* Qp = (unsigned short*)(w);                      //  8 MiB (AO overlays after k_fattn)
    unsigned short* Kp = (unsigned short*)(w + (8u  << 20));        //  8 MiB
    unsigned short* Vt = (unsigned short*)(w + (16u << 20));        //  8 MiB
    unsigned short* Wb = (unsigned short*)(w + (24u << 20));        //  2 MiB
    unsigned short* Op = (unsigned short*)(w + (26u << 20));        // 32 MiB (8 planes)
    unsigned short* AO = Qp;                                        // reuse (Qp dead post-attn)

    k_proj2 <<<dim3(128, 3, 4), dim3(128),  0, stream>>>(q, k, v, Wq, Wk, Wv, Qp, Kp, Vt);
    k_cvtw  <<<dim3(1024),      dim3(256),  0, stream>>>(Wfc, Wb);
    k_fattn <<<dim3(256),       dim3(1024), 0, stream>>>(Qp, Kp, Vt, Op);
    k_merge4<<<dim3(2048),      dim3(256),  0, stream>>>(Op, AO);
    k_fc    <<<dim3(32, 16),    dim3(256),  0, stream>>>(AO, Wb, bfc, (float*)d_out);
}

// Round 10
// 343.689 us; speedup vs baseline: 1.0112x; 1.0112x over previous
//
#include <hip/hip_runtime.h>
#include <hip/hip_bf16.h>

#define S_LEN 2048
#define NHEAD 16
#define HDIM 64
#define EMB 1024

typedef short v8s __attribute__((ext_vector_type(8)));
typedef float v4f __attribute__((ext_vector_type(4)));

__device__ __forceinline__ float bflo(unsigned u) {
    union { unsigned u; float f; } v; v.u = u << 16; return v.f;
}
__device__ __forceinline__ float bfhi(unsigned u) {
    union { unsigned u; float f; } v; v.u = u & 0xFFFF0000u; return v.f;
}
// packed f32x2 -> bf16x2 (v_cvt_pk_bf16_f32 on gfx950), RNE
__device__ __forceinline__ unsigned cvtpk(float lo, float hi) {
    union { __hip_bfloat162 h2; unsigned u; } v;
    float2 f; f.x = lo; f.y = hi;
    v.h2 = __float22bfloat162_rn(f);
    return v.u;
}
__device__ __forceinline__ unsigned short f2bf(float f) {
    return (unsigned short)cvtpk(f, f);
}
__device__ __forceinline__ v8s cvt8(float4 a, float4 b) {
    v8s r;
    ((unsigned*)&r)[0] = cvtpk(a.x, a.y);
    ((unsigned*)&r)[1] = cvtpk(a.z, a.w);
    ((unsigned*)&r)[2] = cvtpk(b.x, b.y);
    ((unsigned*)&r)[3] = cvtpk(b.z, b.w);
    return r;
}

// ---------------------------------------------------------------------------
// K1: MFMA projections. Q/K epilogue bounces through LDS (R8); V epilogue now
// also bounced: stage 64d x 16s tile (stride 20 shorts, 8B-aligned) then
// coalesced uint2 stores (was 16 scattered b16 stores per head).
// ---------------------------------------------------------------------------
__global__ __launch_bounds__(128) void k_proj2(
    const float* __restrict__ q, const float* __restrict__ k, const float* __restrict__ v,
    const float* __restrict__ Wq, const float* __restrict__ Wk, const float* __restrict__ Wv,
    unsigned short* __restrict__ Qp, unsigned short* __restrict__ Kp, unsigned short* __restrict__ Vt)
{
    __shared__ unsigned short Tb[2][1280];         // union: Q/K tile [16][72] / V tile [64][20]
    const int t = threadIdx.x, wave = t >> 6, lane = t & 63;
    const int l15 = lane & 15, l4 = lane >> 4;
    const int mtx = blockIdx.y;
    const int hq = blockIdx.z;
    const int row0 = blockIdx.x * 32 + wave * 16;
    const int b = row0 >> 11, s0 = row0 & 2047;
    const float* X = (mtx == 0) ? q : (mtx == 1) ? k : v;
    const float* W = (mtx == 0) ? Wq : (mtx == 1) ? Wk : Wv;

    v8s wf[4][2];
    #pragma unroll
    for (int tile = 0; tile < 4; ++tile)
        #pragma unroll
        for (int c2 = 0; c2 < 2; ++c2) {
            const float* wp = W + (tile * 16 + l15) * 64 + c2 * 32 + l4 * 8;
            wf[tile][c2] = cvt8(*(const float4*)wp, *(const float4*)(wp + 4));
        }

    #pragma unroll
    for (int hi = 0; hi < 4; ++hi) {
        const int h = hq * 4 + hi;
        v8s xf[2];
        #pragma unroll
        for (int c2 = 0; c2 < 2; ++c2) {
            const float* xp = X + (size_t)(row0 + l15) * EMB + h * 64 + c2 * 32 + l4 * 8;
            xf[c2] = cvt8(*(const float4*)xp, *(const float4*)(xp + 4));
        }
        v4f acc[4];
        #pragma unroll
        for (int i = 0; i < 4; ++i) acc[i] = (v4f){0.f, 0.f, 0.f, 0.f};
        if (mtx < 2) {
            #pragma unroll
            for (int ns = 0; ns < 4; ++ns)
                #pragma unroll
                for (int c2 = 0; c2 < 2; ++c2)
                    acc[ns] = __builtin_amdgcn_mfma_f32_16x16x32_bf16(xf[c2], wf[ns][c2], acc[ns], 0, 0, 0);
            #pragma unroll
            for (int ns = 0; ns < 4; ++ns)
                #pragma unroll
                for (int r = 0; r < 4; ++r)
                    Tb[wave][(l4 * 4 + r) * 72 + ns * 16 + l15] = f2bf(acc[ns][r]);
            const int row = lane >> 2, c8 = (lane & 3) * 16;
            uint4 d0 = *(const uint4*)&Tb[wave][row * 72 + c8];
            uint4 d1 = *(const uint4*)&Tb[wave][row * 72 + c8 + 8];
            unsigned short* dst = ((mtx == 0) ? Qp : Kp)
                + (size_t)(b * NHEAD + h) * S_LEN * HDIM + (size_t)(s0 + row) * HDIM + c8;
            *(uint4*)dst = d0;
            *(uint4*)(dst + 8) = d1;
        } else {
            #pragma unroll
            for (int ms = 0; ms < 4; ++ms)
                #pragma unroll
                for (int c2 = 0; c2 < 2; ++c2)
                    acc[ms] = __builtin_amdgcn_mfma_f32_16x16x32_bf16(wf[ms][c2], xf[c2], acc[ms], 0, 0, 0);
            // stage transposed V tile: rows d (64), cols s (16), stride 20
            #pragma unroll
            for (int ms = 0; ms < 4; ++ms)
                #pragma unroll
                for (int r = 0; r < 4; ++r)
                    Tb[wave][(ms * 16 + l4 * 4 + r) * 20 + l15] = f2bf(acc[ms][r]);
            unsigned short* dst = Vt + (size_t)(b * NHEAD + h) * HDIM * S_LEN + s0;
            #pragma unroll
            for (int it = 0; it < 4; ++it) {
                const int dr = it * 16 + (lane >> 2), cc = (lane & 3) * 4;
                uint2 dv = *(const uint2*)&Tb[wave][dr * 20 + cc];
                *(uint2*)(dst + (size_t)dr * S_LEN + cc) = dv;
            }
        }
    }
}

// ---------------------------------------------------------------------------
// K1c: W_fc fp32 -> bf16
// ---------------------------------------------------------------------------
__global__ __launch_bounds__(256) void k_cvtw(
    const float* __restrict__ W, unsigned short* __restrict__ Wb)
{
    const int i = (blockIdx.x * 256 + threadIdx.x) * 4;
    float4 wv = *(const float4*)(W + i);
    uint2 pk;
    pk.x = cvtpk(wv.x, wv.y);
    pk.y = cvtpk(wv.z, wv.w);
    *(uint2*)(Wb + i) = pk;
}

// ---------------------------------------------------------------------------
// K2: fused attention v4 = R8 skeleton + S^T orientation.
// Phase 1 computes S^T = K·Q^T (operand swap, no extra regs): C-frag holds 4
// CONSECUTIVE k at one q -> ONE ds_write_b64 per fragment (8/c-iter vs R8's 32
// scalar b16). Pex layout [64 q][8 k-slots uint2], row stride 10 (80 B: b128-
// aligned, <=2-way banks). Phase 3 structurally identical to R8 (pu/zv uint4 +
// same VALU) -> register profile == R8's proven 64-VGPR fit (R9 spilled by
// exceeding it; tripwire = FETCH_SIZE). LDS 87040 B, 1 block/CU, 16 waves.
// ---------------------------------------------------------------------------
__global__ __launch_bounds__(1024, 4) void k_fattn(
    const unsigned short* __restrict__ Qp, const unsigned short* __restrict__ Kp,
    const unsigned short* __restrict__ Vt, unsigned short* __restrict__ Op)
{
    __shared__ uint2 PexU[16][640];   // 81920 B: head-plane = 64 q-rows x stride 10
    __shared__ uint2 ZrU[640];        //  5120 B: mirror layout of one head-plane
    const int t = threadIdx.x, wave = t >> 6, lane = t & 63;
    const int l15 = lane & 15, l4 = lane >> 4;
    const int h = wave;
    const int id = blockIdx.x;
    const int slot = id & 7;
    const int kqb = slot & 3;
    const int bsel = slot >> 2;
    const int qt = bsel * 32 + (id >> 3);
    const int b = qt >> 5;
    const int q0 = (qt & 31) * 64;
    const unsigned short* qh = Qp + (size_t)(b * NHEAD + h) * S_LEN * HDIM;
    const unsigned short* kh = Kp + (size_t)(b * NHEAD + h) * S_LEN * HDIM;
    const unsigned short* vh = Vt + (size_t)(b * NHEAD + h) * HDIM * S_LEN;

    v8s aq[4][2];
    #pragma unroll
    for (int qs = 0; qs < 4; ++qs)
        #pragma unroll
        for (int c2 = 0; c2 < 2; ++c2)
            aq[qs][c2] = *(const v8s*)(qh + (size_t)(q0 + qs * 16 + l15) * HDIM + c2 * 32 + l4 * 8);

    v4f o[4][4];
    #pragma unroll
    for (int qs = 0; qs < 4; ++qs)
        #pragma unroll
        for (int ds = 0; ds < 4; ++ds)
            o[qs][ds] = (v4f){0.f, 0.f, 0.f, 0.f};

    uint2* myP = &PexU[h][0];
    const float SC = 0.03125f;

    for (int c = 0; c < 16; ++c) {
        const int kk0 = kqb * 512 + c * 32;
        // ---- phase 1: S^T = K·Q^T, exp -> one b64 store per fragment ----
        #pragma unroll
        for (int ks = 0; ks < 2; ++ks) {
            const unsigned short* kb = kh + (size_t)(kk0 + ks * 16 + l15) * HDIM + l4 * 8;
            v8s ka0 = *(const v8s*)kb;
            v8s ka1 = *(const v8s*)(kb + 32);
            #pragma unroll
            for (int qs = 0; qs < 4; ++qs) {
                v4f sf = (v4f){0.f, 0.f, 0.f, 0.f};
                sf = __builtin_amdgcn_mfma_f32_16x16x32_bf16(ka0, aq[qs][0], sf, 0, 0, 0);
                sf = __builtin_amdgcn_mfma_f32_16x16x32_bf16(ka1, aq[qs][1], sf, 0, 0, 0);
                uint2 pe;
                pe.x = cvtpk(__expf(sf[0] * SC), __expf(sf[1] * SC));
                pe.y = cvtpk(__expf(sf[2] * SC), __expf(sf[3] * SC));
                myP[(qs * 16 + l15) * 10 + ks * 4 + l4] = pe;   // 4 consecutive k @ q
            }
        }
        __syncthreads();
        // ---- phase 2 (t<512): Zr = 1/sum_h exp over the 16 head-planes ----
        if (t < 512) {
            const int idx = (t >> 3) * 10 + (t & 7);
            uint2 u = PexU[0][idx];
            float z0 = bflo(u.x), z1 = bfhi(u.x), z2 = bflo(u.y), z3 = bfhi(u.y);
            #pragma unroll
            for (int hh = 1; hh < 16; ++hh) {
                u = PexU[hh][idx];
                z0 += bflo(u.x); z1 += bfhi(u.x); z2 += bflo(u.y); z3 += bfhi(u.y);
            }
            uint2 zo;
            zo.x = cvtpk(__builtin_amdgcn_rcpf(z0), __builtin_amdgcn_rcpf(z1));
            zo.y = cvtpk(__builtin_amdgcn_rcpf(z2), __builtin_amdgcn_rcpf(z3));
            ZrU[idx] = zo;
        }
        __syncthreads();
        // ---- phase 3: pn = P .* Zr (A-frag b128 reads), O += P·V ----
        {
            v8s bv[4];
            #pragma unroll
            for (int ds = 0; ds < 4; ++ds)
                bv[ds] = *(const v8s*)(vh + (size_t)(ds * 16 + l15) * S_LEN + kk0 + l4 * 8);
            #pragma unroll
            for (int qs = 0; qs < 4; ++qs) {
                const int base = (qs * 16 + l15) * 10 + l4 * 2;
                uint4 pu = *(const uint4*)&myP[base];
                uint4 zv = *(const uint4*)&ZrU[base];
                v8s pn;
                ((unsigned*)&pn)[0] = cvtpk(bflo(pu.x) * bflo(zv.x), bfhi(pu.x) * bfhi(zv.x));
                ((unsigned*)&pn)[1] = cvtpk(bflo(pu.y) * bflo(zv.y), bfhi(pu.y) * bfhi(zv.y));
                ((unsigned*)&pn)[2] = cvtpk(bflo(pu.z) * bflo(zv.z), bfhi(pu.z) * bfhi(zv.z));
                ((unsigned*)&pn)[3] = cvtpk(bflo(pu.w) * bflo(zv.w), bfhi(pu.w) * bfhi(zv.w));
                #pragma unroll
                for (int ds = 0; ds < 4; ++ds)
                    o[qs][ds] = __builtin_amdgcn_mfma_f32_16x16x32_bf16(pn, bv[ds], o[qs][ds], 0, 0, 0);
            }
        }
        // no 3rd barrier: myP plane is wave-private; ZrU rewrite is ordered by
        // the next iteration's two barriers.
    }

    // partial O plane for this (k-quarter, b), bf16 (R8 epilogue)
    unsigned short* op = Op + (size_t)(kqb * 2 + b) * S_LEN * EMB;
    #pragma unroll
    for (int qs = 0; qs < 4; ++qs)
        #pragma unroll
        for (int ds = 0; ds < 4; ++ds)
            #pragma unroll
            for (int r = 0; r < 4; ++r)
                op[(size_t)(q0 + qs * 16 + l4 * 4 + r) * EMB + h * 64 + ds * 16 + l15] =
                    f2bf(o[qs][ds][r]);
}

// ---------------------------------------------------------------------------
// K2b: merge the 4 k-quarter partials -> AO[b*2048+s][e] bf16
// ---------------------------------------------------------------------------
__global__ __launch_bounds__(256) void k_merge4(
    const unsigned short* __restrict__ Op, unsigned short* __restrict__ AO)
{
    const size_t i = ((size_t)blockIdx.x * 256 + threadIdx.x) * 8;
    const size_t row = i >> 10;
    const int b = (int)(row >> 11);
    const size_t off = (row & 2047) * EMB + (i & 1023);
    float a0 = 0, a1 = 0, a2 = 0, a3 = 0, a4 = 0, a5 = 0, a6 = 0, a7 = 0;
    #pragma unroll
    for (int kq = 0; kq < 4; ++kq) {
        uint4 u = *(const uint4*)(Op + (size_t)(kq * 2 + b) * S_LEN * EMB + off);
        a0 += bflo(u.x); a1 += bfhi(u.x);
        a2 += bflo(u.y); a3 += bfhi(u.y);
        a4 += bflo(u.z); a5 += bfhi(u.z);
        a6 += bflo(u.w); a7 += bfhi(u.w);
    }
    uint4 r;
    r.x = cvtpk(a0, a1); r.y = cvtpk(a2, a3);
    r.z = cvtpk(a4, a5); r.w = cvtpk(a6, a7);
    *(uint4*)(AO + i) = r;
}

// ---------------------------------------------------------------------------
// K4: out = AO @ W_fc^T + b_fc  (unchanged from R8)
// ---------------------------------------------------------------------------
__global__ __launch_bounds__(256) void k_fc(
    const unsigned short* __restrict__ AO, const unsigned short* __restrict__ Wb,
    const float* __restrict__ bias, float* __restrict__ out)
{
    const int t = threadIdx.x, wave = t >> 6, lane = t & 63;
    const int l15 = lane & 15, l4 = lane >> 4;
    const int m0 = blockIdx.x * 128 + wave * 32;
    const int n0 = blockIdx.y * 64;
    v4f c[2][4];
    #pragma unroll
    for (int i = 0; i < 2; ++i)
        #pragma unroll
        for (int j = 0; j < 4; ++j) c[i][j] = (v4f){0.f, 0.f, 0.f, 0.f};
    for (int k = 0; k < EMB; k += 32) {
        v8s a0 = *(const v8s*)(AO + (size_t)(m0 + l15) * EMB + k + l4 * 8);
        v8s a1 = *(const v8s*)(AO + (size_t)(m0 + 16 + l15) * EMB + k + l4 * 8);
        #pragma unroll
        for (int ns = 0; ns < 4; ++ns) {
            v8s bw = *(const v8s*)(Wb + (size_t)(n0 + ns * 16 + l15) * EMB + k + l4 * 8);
            c[0][ns] = __builtin_amdgcn_mfma_f32_16x16x32_bf16(a0, bw, c[0][ns], 0, 0, 0);
            c[1][ns] = __builtin_amdgcn_mfma_f32_16x16x32_bf16(a1, bw, c[1][ns], 0, 0, 0);
        }
    }
    #pragma unroll
    for (int ms = 0; ms < 2; ++ms)
        #pragma unroll
        for (int ns = 0; ns < 4; ++ns) {
            const float bv = bias[n0 + ns * 16 + l15];
            #pragma unroll
            for (int r = 0; r < 4; ++r)
                out[(size_t)(m0 + ms * 16 + l4 * 4 + r) * EMB + n0 + ns * 16 + l15] = c[ms][ns][r] + bv;
        }
}

extern "C" void kernel_launch(void* const* d_in, const int* in_sizes, int n_in,
                              void* d_out, int out_size, void* d_ws, size_t ws_size,
                              hipStream_t stream)
{
    (void)in_sizes; (void)n_in; (void)out_size; (void)ws_size;
    const float* q   = (const float*)d_in[0];
    const float* k   = (const float*)d_in[1];
    const float* v   = (const float*)d_in[2];
    const float* Wq  = (const float*)d_in[3];
    const float* Wk  = (const float*)d_in[4];
    const float* Wv  = (const float*)d_in[5];
    const float* Wfc = (const float*)d_in[6];
    const float* bfc = (const float*)d_in[7];

    char* w = (char*)d_ws;
    unsigned short* Qp = (unsigned short*)(w);                      //  8 MiB (AO overlays after k_fattn)
    unsigned short* Kp = (unsigned short*)(w + (8u  << 20));        //  8 MiB
    unsigned short* Vt = (unsigned short*)(w + (16u << 20));        //  8 MiB
    unsigned short* Wb = (unsigned short*)(w + (24u << 20));        //  2 MiB
    unsigned short* Op = (unsigned short*)(w + (26u << 20));        // 32 MiB (8 planes)
    unsigned short* AO = Qp;                                        // reuse (Qp dead post-attn)

    k_proj2 <<<dim3(128, 3, 4), dim3(128),  0, stream>>>(q, k, v, Wq, Wk, Wv, Qp, Kp, Vt);
    k_cvtw  <<<dim3(1024),      dim3(256),  0, stream>>>(Wfc, Wb);
    k_fattn <<<dim3(256),       dim3(1024), 0, stream>>>(Qp, Kp, Vt, Op);
    k_merge4<<<dim3(2048),      dim3(256),  0, stream>>>(Op, AO);
    k_fc    <<<dim3(32, 16),    dim3(256),  0, stream>>>(AO, Wb, bfc, (float*)d_out);
}